// Round 11
// baseline (636.699 us; speedup 1.0000x reference)
//
#include <hip/hip_runtime.h>

// CentroidPool: N=65536 x K=4096 x D=128 fp32 -> argmin_k ||x - c_k|| (int32).
// Stage 1: f16x3-split MFMA GEMM (xh*ch + xh*cl + xl*ch, fp32 acc = c2 init),
//   top-2 via sortable packed keys (score bits | tile id), 4 VALU ops/slot.
//   B-stream software-pipelined (register ping-pong). ROUND-10 LESSON: the
//   ping-pong buffers MUST be named scalars touched only via macros — passing
//   local arrays by pointer into a lambda blocked SROA, putting Ba/Bb in
//   scratch (FETCH 1.08 GB / WRITE 511 MB of spill traffic, 571 us).
// Stage 2: exact fp64 rescore of the 2 candidates (near-tie rescue).

typedef _Float16 f16;
typedef f16  f16x8 __attribute__((ext_vector_type(8)));
typedef float f32x4 __attribute__((ext_vector_type(4)));

constexpr int N_PTS  = 65536;
constexpr int K_CENT = 4096;
constexpr int D_DIM  = 128;
constexpr int MB     = 64;     // points per block (4 waves share them)
constexpr int KW     = 1024;   // centroids per wave (waves split K 4-ways)
constexpr float SOFF = 256.0f; // score offset => strictly positive scores

// ---------------------------------------------------------------------------
__global__ __launch_bounds__(256) void c2_kernel(const float* __restrict__ coords,
                                                 float* __restrict__ c2b) {
    int k = blockIdx.x * 256 + threadIdx.x;
    const float* c = coords + (size_t)k * D_DIM;
    float s = 0.f;
#pragma unroll
    for (int d = 0; d < D_DIM; ++d) s = fmaf(c[d], c[d], s);
    c2b[k] = s + SOFF;
}

__global__ __launch_bounds__(256) void split_coords(const float* __restrict__ c,
                                                    f16* __restrict__ ch,
                                                    f16* __restrict__ cl) {
    int e = blockIdx.x * 256 + threadIdx.x;
    float x = c[e];
    f16 h = (f16)x;
    ch[e] = h;
    cl[e] = (f16)(x - (float)h);
}

// ---------------------------------------------------------------------------
// Stage 1. Block = 4 waves x 64 points; latent (-2x) split h/l in XOR-swizzled
// LDS (stride 128 f16, 16-B unit col8 ^= row&15 -> conflict-free reads).
// Wave w scans cents [w*1024,(w+1)*1024) in 32-wide k-tiles (2 n-groups).
// Ping-pong invariant at tile top: Ba = (kt, ds0), offB -> (kt, ds1).
// key = (bits(score)&~63)|kn, kn = kt*2+n (6b); cent = (wave*64+kn)*16 + l15.
// ---------------------------------------------------------------------------
__global__ __launch_bounds__(256, 3) void argmin_mfma(
        const float* __restrict__ latent,
        const f16*   __restrict__ ch,
        const f16*   __restrict__ cl,
        const float* __restrict__ c2b,
        int* __restrict__ top1,
        int* __restrict__ top2) {
    __shared__ f16 latH[MB * 128];
    __shared__ f16 latL[MB * 128];
    __shared__ unsigned r1K[4][MB]; __shared__ int r1I[4][MB];
    __shared__ unsigned r2K[4][MB]; __shared__ int r2I[4][MB];

    const int t    = threadIdx.x;
    const int wave = t >> 6;
    const int lane = t & 63;
    const int quad = lane >> 4;
    const int l15  = lane & 15;
    const int row0 = blockIdx.x * MB;

    {   // Stage latent: scale -2, split h/l, XOR-swizzle 16-B units.
        const float4* src = (const float4*)(latent + (size_t)row0 * D_DIM);
#pragma unroll
        for (int i = 0; i < 4; ++i) {
            int g  = i * 256 + t;          // float8 index in [0,1024)
            int r  = g >> 4;               // row (16 float8 per row)
            int c8 = g & 15;               // logical 16-B column
            float4 v0 = src[2 * g];
            float4 v1 = src[2 * g + 1];
            float xs[8] = {v0.x, v0.y, v0.z, v0.w, v1.x, v1.y, v1.z, v1.w};
            f16x8 hv, lv;
#pragma unroll
            for (int c = 0; c < 8; ++c) {
                float x = -2.0f * xs[c];
                f16 h = (f16)x;
                hv[c] = h;
                lv[c] = (f16)(x - (float)h);
            }
            int pc = ((c8 ^ (r & 15)) << 3);
            *(f16x8*)&latH[r * 128 + pc] = hv;
            *(f16x8*)&latL[r * 128 + pc] = lv;
        }
    }
    __syncthreads();

    unsigned b1[16], b2[16];
#pragma unroll
    for (int i = 0; i < 16; ++i) { b1[i] = 0xFFFFFFFFu; b2[i] = 0xFFFFFFFFu; }

    const int wbase = wave * KW;
    unsigned offB = (unsigned)(wbase + l15) * 128u + (unsigned)(quad * 8);

    // Named ping-pong regs — NEVER address-taken (SROA must keep them in VGPRs).
    f16x8 Ba0, Ba1, Ba2, Ba3, Bb0, Bb1, Bb2, Bb3;
    f32x4 a00, a01, a10, a11, a20, a21, a30, a31;

#define PFB(P) \
    P##0 = *(const f16x8*)(ch + offB); \
    P##1 = *(const f16x8*)(cl + offB); \
    P##2 = *(const f16x8*)(ch + offB + 2048); \
    P##3 = *(const f16x8*)(cl + offB + 2048);

#define MF(d, a, b) d = __builtin_amdgcn_mfma_f32_16x16x32_f16(a, b, d, 0, 0, 0);

#define STEP(P, ds) { \
    const int pc_ = ((((ds) << 2) + quad) ^ l15) << 3; \
    f16x8 ah_, al_; \
    ah_ = *(const f16x8*)&latH[(     l15) * 128 + pc_]; \
    al_ = *(const f16x8*)&latL[(     l15) * 128 + pc_]; \
    MF(a00, ah_, P##0) MF(a00, ah_, P##1) MF(a00, al_, P##0) \
    MF(a01, ah_, P##2) MF(a01, ah_, P##3) MF(a01, al_, P##2) \
    ah_ = *(const f16x8*)&latH[(16 + l15) * 128 + pc_]; \
    al_ = *(const f16x8*)&latL[(16 + l15) * 128 + pc_]; \
    MF(a10, ah_, P##0) MF(a10, ah_, P##1) MF(a10, al_, P##0) \
    MF(a11, ah_, P##2) MF(a11, ah_, P##3) MF(a11, al_, P##2) \
    ah_ = *(const f16x8*)&latH[(32 + l15) * 128 + pc_]; \
    al_ = *(const f16x8*)&latL[(32 + l15) * 128 + pc_]; \
    MF(a20, ah_, P##0) MF(a20, ah_, P##1) MF(a20, al_, P##0) \
    MF(a21, ah_, P##2) MF(a21, ah_, P##3) MF(a21, al_, P##2) \
    ah_ = *(const f16x8*)&latH[(48 + l15) * 128 + pc_]; \
    al_ = *(const f16x8*)&latL[(48 + l15) * 128 + pc_]; \
    MF(a30, ah_, P##0) MF(a30, ah_, P##1) MF(a30, al_, P##0) \
    MF(a31, ah_, P##2) MF(a31, ah_, P##3) MF(a31, al_, P##2) }

#define INS1(s, kn, slot) { \
    unsigned key_ = (__float_as_uint(s) & 0xFFFFFFC0u) | (kn); \
    unsigned hi_ = key_ > b1[slot] ? key_ : b1[slot]; \
    b1[slot] = key_ < b1[slot] ? key_ : b1[slot]; \
    b2[slot] = hi_  < b2[slot] ? hi_  : b2[slot]; }

#define INS4(av, kn, m) \
    INS1(av[0], kn, (m) * 4 + 0) INS1(av[1], kn, (m) * 4 + 1) \
    INS1(av[2], kn, (m) * 4 + 2) INS1(av[3], kn, (m) * 4 + 3)

    // Prime: load (kt=0, ds=0) into Ba; offB -> (0, ds1).
    PFB(Ba)
    offB += 32;
    float cv0 = c2b[wbase + l15];
    float cv1 = c2b[wbase + 16 + l15];

#pragma unroll 1
    for (int kt = 0; kt < KW / 32; ++kt) {
        a00 = (f32x4){cv0, cv0, cv0, cv0}; a01 = (f32x4){cv1, cv1, cv1, cv1};
        a10 = a00; a11 = a01; a20 = a00; a21 = a01; a30 = a00; a31 = a01;

        int ktn = (kt + 1) & 31;    // wraps at end; value then unused
        float cvn0 = c2b[wbase + ktn * 32 + l15];
        float cvn1 = c2b[wbase + ktn * 32 + 16 + l15];

        PFB(Bb) offB += 32;            STEP(Ba, 0)   // loads (kt,ds1)
        PFB(Ba) offB += 32;            STEP(Bb, 1)   // loads (kt,ds2)
        PFB(Bb) offB += 32 * 128 - 96; STEP(Ba, 2)   // loads (kt,ds3); -> (kt+1,ds0)
        if (kt != KW / 32 - 1) { PFB(Ba) }           // loads (kt+1,ds0)
        offB += 32;                                  // -> (kt+1,ds1)
        STEP(Bb, 3)

        const unsigned kn0 = (unsigned)(kt * 2);
        const unsigned kn1 = kn0 + 1u;
        INS4(a00, kn0, 0) INS4(a10, kn0, 1) INS4(a20, kn0, 2) INS4(a30, kn0, 3)
        INS4(a01, kn1, 0) INS4(a11, kn1, 1) INS4(a21, kn1, 2) INS4(a31, kn1, 3)

        cv0 = cvn0; cv1 = cvn1;
    }

    // Quad butterfly: merge two sorted-2 (key,idx) lists per step.
#pragma unroll
    for (int m = 0; m < 4; ++m)
#pragma unroll
        for (int r = 0; r < 4; ++r) {
            unsigned k1 = b1[m * 4 + r], k2 = b2[m * 4 + r];
            int i1 = ((wave * 64 + (int)(k1 & 63u)) << 4) | l15;
            int i2 = ((wave * 64 + (int)(k2 & 63u)) << 4) | l15;
#pragma unroll
            for (int msk = 1; msk < 16; msk <<= 1) {
                unsigned ok1 = (unsigned)__shfl_xor((int)k1, msk, 64);
                int      oi1 = __shfl_xor(i1, msk, 64);
                unsigned ok2 = (unsigned)__shfl_xor((int)k2, msk, 64);
                int      oi2 = __shfl_xor(i2, msk, 64);
                bool ow = ok1 < k1;
                unsigned w1k = ow ? ok1 : k1; int w1i = ow ? oi1 : i1;
                unsigned lsk = ow ? k1 : ok1; int lsi = ow ? i1 : oi1;
                unsigned wsk = ow ? ok2 : k2; int wsi = ow ? oi2 : i2;
                bool sw = lsk < wsk;
                k1 = w1k; i1 = w1i;
                k2 = sw ? lsk : wsk; i2 = sw ? lsi : wsi;
            }
            if (l15 == 0) {
                int p = m * 16 + quad * 4 + r;
                r1K[wave][p] = k1; r1I[wave][p] = i1;
                r2K[wave][p] = k2; r2I[wave][p] = i2;
            }
        }
    __syncthreads();

    if (t < MB) {
        unsigned k1 = r1K[0][t], k2 = r2K[0][t];
        int      i1 = r1I[0][t], i2 = r2I[0][t];
#pragma unroll
        for (int w = 1; w < 4; ++w) {
            unsigned ok1 = r1K[w][t], ok2 = r2K[w][t];
            int      oi1 = r1I[w][t], oi2 = r2I[w][t];
            bool ow = ok1 < k1;
            unsigned w1k = ow ? ok1 : k1; int w1i = ow ? oi1 : i1;
            unsigned lsk = ow ? k1 : ok1; int lsi = ow ? i1 : oi1;
            unsigned wsk = ow ? ok2 : k2; int wsi = ow ? oi2 : i2;
            bool sw = lsk < wsk;
            k1 = w1k; i1 = w1i;
            k2 = sw ? lsk : wsk; i2 = sw ? lsi : wsi;
        }
        top1[row0 + t] = i1;
        top2[row0 + t] = i2;
    }
}

// ---------------------------------------------------------------------------
// Stage 2: exact fp64 rescore of the two candidates; true winner wins
// (idx tie -> smaller index).
// ---------------------------------------------------------------------------
__global__ __launch_bounds__(256) void rescore(const float* __restrict__ latent,
                                               const float* __restrict__ coords,
                                               const int* __restrict__ top1,
                                               const int* __restrict__ top2,
                                               int* __restrict__ out) {
    int n = blockIdx.x * 256 + threadIdx.x;
    int i1 = top1[n], i2 = top2[n];
    const float* x  = latent + (size_t)n * D_DIM;
    const float* ca = coords + (size_t)i1 * D_DIM;
    const float* cb = coords + (size_t)i2 * D_DIM;
    double d1 = 0.0, d2 = 0.0;
#pragma unroll
    for (int d = 0; d < D_DIM; d += 4) {
        float4 xv = *(const float4*)(x + d);
        float4 av = *(const float4*)(ca + d);
        float4 bv = *(const float4*)(cb + d);
        double e;
        e = (double)xv.x - (double)av.x; d1 += e * e;
        e = (double)xv.y - (double)av.y; d1 += e * e;
        e = (double)xv.z - (double)av.z; d1 += e * e;
        e = (double)xv.w - (double)av.w; d1 += e * e;
        e = (double)xv.x - (double)bv.x; d2 += e * e;
        e = (double)xv.y - (double)bv.y; d2 += e * e;
        e = (double)xv.z - (double)bv.z; d2 += e * e;
        e = (double)xv.w - (double)bv.w; d2 += e * e;
    }
    bool second = (d2 < d1) || (d2 == d1 && i2 < i1);
    out[n] = second ? i2 : i1;
}

// ---------------------------------------------------------------------------
extern "C" void kernel_launch(void* const* d_in, const int* in_sizes, int n_in,
                              void* d_out, int out_size, void* d_ws, size_t ws_size,
                              hipStream_t stream) {
    const float* latent = (const float*)d_in[0];
    const float* coords = (const float*)d_in[1];
    int* out = (int*)d_out;

    // ws: ch [K*D] f16 | cl [K*D] f16 | c2b [K] f32 | top1 [N] | top2 [N]
    f16*   ch  = (f16*)d_ws;
    f16*   cl  = ch + (size_t)K_CENT * D_DIM;
    float* c2b = (float*)(cl + (size_t)K_CENT * D_DIM);
    int*   t1  = (int*)(c2b + K_CENT);
    int*   t2  = t1 + N_PTS;

    c2_kernel<<<dim3(K_CENT / 256), dim3(256), 0, stream>>>(coords, c2b);
    split_coords<<<dim3(K_CENT * D_DIM / 256), dim3(256), 0, stream>>>(coords, ch, cl);
    argmin_mfma<<<dim3(N_PTS / MB), dim3(256), 0, stream>>>(latent, ch, cl, c2b, t1, t2);
    rescore<<<dim3(N_PTS / 256), dim3(256), 0, stream>>>(latent, coords, t1, t2, out);
}

// Round 12
// 333.761 us; speedup vs baseline: 1.9076x; 1.9076x over previous
//
#include <hip/hip_runtime.h>

// CentroidPool: N=65536 x K=4096 x D=128 fp32 -> argmin_k ||x - c_k|| (int32).
// Stage 1: f16x3-split MFMA GEMM (xh*ch + xh*cl + xl*ch, fp32 acc = c2 init),
//   top-2 via sortable packed keys (score bits | tile id), 4 VALU ops/slot.
//   B-stream software-pipelined (register ping-pong).
//   ROUND-11 LESSON: __launch_bounds__(256,3) caps unified regs at ~170 and
//   the compiler splits ~84 VGPR + ~84 AGPR; arch side needs ~116 -> spilled
//   one B-buffer per k-tile (WRITE 516 MB = 64 B x 32 tiles x 262k threads).
//   (256,2) gives a 128/128 split -> fits. Occupancy is the pipeline's job.
// Stage 2: exact fp64 rescore of the 2 candidates (near-tie rescue).

typedef _Float16 f16;
typedef f16  f16x8 __attribute__((ext_vector_type(8)));
typedef float f32x4 __attribute__((ext_vector_type(4)));

constexpr int N_PTS  = 65536;
constexpr int K_CENT = 4096;
constexpr int D_DIM  = 128;
constexpr int MB     = 64;     // points per block (4 waves share them)
constexpr int KW     = 1024;   // centroids per wave (waves split K 4-ways)
constexpr float SOFF = 256.0f; // score offset => strictly positive scores

// ---------------------------------------------------------------------------
__global__ __launch_bounds__(256) void c2_kernel(const float* __restrict__ coords,
                                                 float* __restrict__ c2b) {
    int k = blockIdx.x * 256 + threadIdx.x;
    const float* c = coords + (size_t)k * D_DIM;
    float s = 0.f;
#pragma unroll
    for (int d = 0; d < D_DIM; ++d) s = fmaf(c[d], c[d], s);
    c2b[k] = s + SOFF;
}

__global__ __launch_bounds__(256) void split_coords(const float* __restrict__ c,
                                                    f16* __restrict__ ch,
                                                    f16* __restrict__ cl) {
    int e = blockIdx.x * 256 + threadIdx.x;
    float x = c[e];
    f16 h = (f16)x;
    ch[e] = h;
    cl[e] = (f16)(x - (float)h);
}

// ---------------------------------------------------------------------------
// Stage 1. Block = 4 waves x 64 points; latent (-2x) split h/l in XOR-swizzled
// LDS (stride 128 f16, 16-B unit col8 ^= row&15 -> conflict-free reads).
// Wave w scans cents [w*1024,(w+1)*1024) in 32-wide k-tiles (2 n-groups).
// Ping-pong invariant at tile top: Ba = (kt, ds0), offB -> (kt, ds1).
// key = (bits(score)&~63)|kn, kn = kt*2+n (6b); cent = (wave*64+kn)*16 + l15.
// ---------------------------------------------------------------------------
__global__ __launch_bounds__(256, 2) void argmin_mfma(
        const float* __restrict__ latent,
        const f16*   __restrict__ ch,
        const f16*   __restrict__ cl,
        const float* __restrict__ c2b,
        int* __restrict__ top1,
        int* __restrict__ top2) {
    __shared__ f16 latH[MB * 128];
    __shared__ f16 latL[MB * 128];
    __shared__ unsigned r1K[4][MB]; __shared__ int r1I[4][MB];
    __shared__ unsigned r2K[4][MB]; __shared__ int r2I[4][MB];

    const int t    = threadIdx.x;
    const int wave = t >> 6;
    const int lane = t & 63;
    const int quad = lane >> 4;
    const int l15  = lane & 15;
    const int row0 = blockIdx.x * MB;

    {   // Stage latent: scale -2, split h/l, XOR-swizzle 16-B units.
        const float4* src = (const float4*)(latent + (size_t)row0 * D_DIM);
#pragma unroll
        for (int i = 0; i < 4; ++i) {
            int g  = i * 256 + t;          // float8 index in [0,1024)
            int r  = g >> 4;               // row (16 float8 per row)
            int c8 = g & 15;               // logical 16-B column
            float4 v0 = src[2 * g];
            float4 v1 = src[2 * g + 1];
            float xs[8] = {v0.x, v0.y, v0.z, v0.w, v1.x, v1.y, v1.z, v1.w};
            f16x8 hv, lv;
#pragma unroll
            for (int c = 0; c < 8; ++c) {
                float x = -2.0f * xs[c];
                f16 h = (f16)x;
                hv[c] = h;
                lv[c] = (f16)(x - (float)h);
            }
            int pc = ((c8 ^ (r & 15)) << 3);
            *(f16x8*)&latH[r * 128 + pc] = hv;
            *(f16x8*)&latL[r * 128 + pc] = lv;
        }
    }
    __syncthreads();

    unsigned b1[16], b2[16];
#pragma unroll
    for (int i = 0; i < 16; ++i) { b1[i] = 0xFFFFFFFFu; b2[i] = 0xFFFFFFFFu; }

    const int wbase = wave * KW;
    unsigned offB = (unsigned)(wbase + l15) * 128u + (unsigned)(quad * 8);

    // Named ping-pong regs — never address-taken.
    f16x8 Ba0, Ba1, Ba2, Ba3, Bb0, Bb1, Bb2, Bb3;
    f32x4 a00, a01, a10, a11, a20, a21, a30, a31;

#define PFB(P) \
    P##0 = *(const f16x8*)(ch + offB); \
    P##1 = *(const f16x8*)(cl + offB); \
    P##2 = *(const f16x8*)(ch + offB + 2048); \
    P##3 = *(const f16x8*)(cl + offB + 2048);

#define MF(d, a, b) d = __builtin_amdgcn_mfma_f32_16x16x32_f16(a, b, d, 0, 0, 0);

#define STEP(P, ds) { \
    const int pc_ = ((((ds) << 2) + quad) ^ l15) << 3; \
    f16x8 ah_, al_; \
    ah_ = *(const f16x8*)&latH[(     l15) * 128 + pc_]; \
    al_ = *(const f16x8*)&latL[(     l15) * 128 + pc_]; \
    MF(a00, ah_, P##0) MF(a00, ah_, P##1) MF(a00, al_, P##0) \
    MF(a01, ah_, P##2) MF(a01, ah_, P##3) MF(a01, al_, P##2) \
    ah_ = *(const f16x8*)&latH[(16 + l15) * 128 + pc_]; \
    al_ = *(const f16x8*)&latL[(16 + l15) * 128 + pc_]; \
    MF(a10, ah_, P##0) MF(a10, ah_, P##1) MF(a10, al_, P##0) \
    MF(a11, ah_, P##2) MF(a11, ah_, P##3) MF(a11, al_, P##2) \
    ah_ = *(const f16x8*)&latH[(32 + l15) * 128 + pc_]; \
    al_ = *(const f16x8*)&latL[(32 + l15) * 128 + pc_]; \
    MF(a20, ah_, P##0) MF(a20, ah_, P##1) MF(a20, al_, P##0) \
    MF(a21, ah_, P##2) MF(a21, ah_, P##3) MF(a21, al_, P##2) \
    ah_ = *(const f16x8*)&latH[(48 + l15) * 128 + pc_]; \
    al_ = *(const f16x8*)&latL[(48 + l15) * 128 + pc_]; \
    MF(a30, ah_, P##0) MF(a30, ah_, P##1) MF(a30, al_, P##0) \
    MF(a31, ah_, P##2) MF(a31, ah_, P##3) MF(a31, al_, P##2) }

#define INS1(s, kn, slot) { \
    unsigned key_ = (__float_as_uint(s) & 0xFFFFFFC0u) | (kn); \
    unsigned hi_ = key_ > b1[slot] ? key_ : b1[slot]; \
    b1[slot] = key_ < b1[slot] ? key_ : b1[slot]; \
    b2[slot] = hi_  < b2[slot] ? hi_  : b2[slot]; }

#define INS4(av, kn, m) \
    INS1(av[0], kn, (m) * 4 + 0) INS1(av[1], kn, (m) * 4 + 1) \
    INS1(av[2], kn, (m) * 4 + 2) INS1(av[3], kn, (m) * 4 + 3)

    // Prime: load (kt=0, ds=0) into Ba; offB -> (0, ds1).
    PFB(Ba)
    offB += 32;
    float cv0 = c2b[wbase + l15];
    float cv1 = c2b[wbase + 16 + l15];

#pragma unroll 1
    for (int kt = 0; kt < KW / 32; ++kt) {
        a00 = (f32x4){cv0, cv0, cv0, cv0}; a01 = (f32x4){cv1, cv1, cv1, cv1};
        a10 = a00; a11 = a01; a20 = a00; a21 = a01; a30 = a00; a31 = a01;

        int ktn = (kt + 1) & 31;    // wraps at end; value then unused
        float cvn0 = c2b[wbase + ktn * 32 + l15];
        float cvn1 = c2b[wbase + ktn * 32 + 16 + l15];

        PFB(Bb) offB += 32;            STEP(Ba, 0)   // loads (kt,ds1)
        PFB(Ba) offB += 32;            STEP(Bb, 1)   // loads (kt,ds2)
        PFB(Bb) offB += 32 * 128 - 96; STEP(Ba, 2)   // loads (kt,ds3); -> (kt+1,ds0)
        if (kt != KW / 32 - 1) { PFB(Ba) }           // loads (kt+1,ds0)
        offB += 32;                                  // -> (kt+1,ds1)
        STEP(Bb, 3)

        const unsigned kn0 = (unsigned)(kt * 2);
        const unsigned kn1 = kn0 + 1u;
        INS4(a00, kn0, 0) INS4(a10, kn0, 1) INS4(a20, kn0, 2) INS4(a30, kn0, 3)
        INS4(a01, kn1, 0) INS4(a11, kn1, 1) INS4(a21, kn1, 2) INS4(a31, kn1, 3)

        cv0 = cvn0; cv1 = cvn1;
    }

    // Quad butterfly: merge two sorted-2 (key,idx) lists per step.
#pragma unroll
    for (int m = 0; m < 4; ++m)
#pragma unroll
        for (int r = 0; r < 4; ++r) {
            unsigned k1 = b1[m * 4 + r], k2 = b2[m * 4 + r];
            int i1 = ((wave * 64 + (int)(k1 & 63u)) << 4) | l15;
            int i2 = ((wave * 64 + (int)(k2 & 63u)) << 4) | l15;
#pragma unroll
            for (int msk = 1; msk < 16; msk <<= 1) {
                unsigned ok1 = (unsigned)__shfl_xor((int)k1, msk, 64);
                int      oi1 = __shfl_xor(i1, msk, 64);
                unsigned ok2 = (unsigned)__shfl_xor((int)k2, msk, 64);
                int      oi2 = __shfl_xor(i2, msk, 64);
                bool ow = ok1 < k1;
                unsigned w1k = ow ? ok1 : k1; int w1i = ow ? oi1 : i1;
                unsigned lsk = ow ? k1 : ok1; int lsi = ow ? i1 : oi1;
                unsigned wsk = ow ? ok2 : k2; int wsi = ow ? oi2 : i2;
                bool sw = lsk < wsk;
                k1 = w1k; i1 = w1i;
                k2 = sw ? lsk : wsk; i2 = sw ? lsi : wsi;
            }
            if (l15 == 0) {
                int p = m * 16 + quad * 4 + r;
                r1K[wave][p] = k1; r1I[wave][p] = i1;
                r2K[wave][p] = k2; r2I[wave][p] = i2;
            }
        }
    __syncthreads();

    if (t < MB) {
        unsigned k1 = r1K[0][t], k2 = r2K[0][t];
        int      i1 = r1I[0][t], i2 = r2I[0][t];
#pragma unroll
        for (int w = 1; w < 4; ++w) {
            unsigned ok1 = r1K[w][t], ok2 = r2K[w][t];
            int      oi1 = r1I[w][t], oi2 = r2I[w][t];
            bool ow = ok1 < k1;
            unsigned w1k = ow ? ok1 : k1; int w1i = ow ? oi1 : i1;
            unsigned lsk = ow ? k1 : ok1; int lsi = ow ? i1 : oi1;
            unsigned wsk = ow ? ok2 : k2; int wsi = ow ? oi2 : i2;
            bool sw = lsk < wsk;
            k1 = w1k; i1 = w1i;
            k2 = sw ? lsk : wsk; i2 = sw ? lsi : wsi;
        }
        top1[row0 + t] = i1;
        top2[row0 + t] = i2;
    }
}

// ---------------------------------------------------------------------------
// Stage 2: exact fp64 rescore of the two candidates; true winner wins
// (idx tie -> smaller index).
// ---------------------------------------------------------------------------
__global__ __launch_bounds__(256) void rescore(const float* __restrict__ latent,
                                               const float* __restrict__ coords,
                                               const int* __restrict__ top1,
                                               const int* __restrict__ top2,
                                               int* __restrict__ out) {
    int n = blockIdx.x * 256 + threadIdx.x;
    int i1 = top1[n], i2 = top2[n];
    const float* x  = latent + (size_t)n * D_DIM;
    const float* ca = coords + (size_t)i1 * D_DIM;
    const float* cb = coords + (size_t)i2 * D_DIM;
    double d1 = 0.0, d2 = 0.0;
#pragma unroll
    for (int d = 0; d < D_DIM; d += 4) {
        float4 xv = *(const float4*)(x + d);
        float4 av = *(const float4*)(ca + d);
        float4 bv = *(const float4*)(cb + d);
        double e;
        e = (double)xv.x - (double)av.x; d1 += e * e;
        e = (double)xv.y - (double)av.y; d1 += e * e;
        e = (double)xv.z - (double)av.z; d1 += e * e;
        e = (double)xv.w - (double)av.w; d1 += e * e;
        e = (double)xv.x - (double)bv.x; d2 += e * e;
        e = (double)xv.y - (double)bv.y; d2 += e * e;
        e = (double)xv.z - (double)bv.z; d2 += e * e;
        e = (double)xv.w - (double)bv.w; d2 += e * e;
    }
    bool second = (d2 < d1) || (d2 == d1 && i2 < i1);
    out[n] = second ? i2 : i1;
}

// ---------------------------------------------------------------------------
extern "C" void kernel_launch(void* const* d_in, const int* in_sizes, int n_in,
                              void* d_out, int out_size, void* d_ws, size_t ws_size,
                              hipStream_t stream) {
    const float* latent = (const float*)d_in[0];
    const float* coords = (const float*)d_in[1];
    int* out = (int*)d_out;

    // ws: ch [K*D] f16 | cl [K*D] f16 | c2b [K] f32 | top1 [N] | top2 [N]
    f16*   ch  = (f16*)d_ws;
    f16*   cl  = ch + (size_t)K_CENT * D_DIM;
    float* c2b = (float*)(cl + (size_t)K_CENT * D_DIM);
    int*   t1  = (int*)(c2b + K_CENT);
    int*   t2  = t1 + N_PTS;

    c2_kernel<<<dim3(K_CENT / 256), dim3(256), 0, stream>>>(coords, c2b);
    split_coords<<<dim3(K_CENT * D_DIM / 256), dim3(256), 0, stream>>>(coords, ch, cl);
    argmin_mfma<<<dim3(N_PTS / MB), dim3(256), 0, stream>>>(latent, ch, cl, c2b, t1, t2);
    rescore<<<dim3(N_PTS / 256), dim3(256), 0, stream>>>(latent, coords, t1, t2, out);
}

// Round 13
// 251.348 us; speedup vs baseline: 2.5331x; 1.3279x over previous
//
#include <hip/hip_runtime.h>

// CentroidPool: N=65536 x K=4096 x D=128 fp32 -> argmin_k ||x - c_k|| (int32).
// Stage 1: f16x3-split MFMA GEMM (xh*ch + xh*cl + xl*ch, fp32 acc = c2 init),
//   top-2 via sortable packed keys, 4 VALU ops/slot, register ping-pong
//   B pipeline. ROUND-13: B pre-packed in per-(tile,step,lane) fragment order
//   -> every B load is 64x16B fully coalesced (round 12 scattered 16 cache
//   lines per load: 256 line-transactions per wave-tile was the wall).
//   offB stride is a uniform +1024 elems/step (no correction terms).
// Stage 2: exact fp64 rescore of the 2 candidates (near-tie rescue).

typedef _Float16 f16;
typedef f16  f16x8 __attribute__((ext_vector_type(8)));
typedef float f32x4 __attribute__((ext_vector_type(4)));

constexpr int N_PTS  = 65536;
constexpr int K_CENT = 4096;
constexpr int D_DIM  = 128;
constexpr int MB     = 64;     // points per block (4 waves share them)
constexpr int KW     = 1024;   // centroids per wave (waves split K 4-ways)
constexpr float SOFF = 256.0f; // score offset => strictly positive scores

// ---------------------------------------------------------------------------
__global__ __launch_bounds__(256) void c2_kernel(const float* __restrict__ coords,
                                                 float* __restrict__ c2b) {
    int k = blockIdx.x * 256 + threadIdx.x;
    const float* c = coords + (size_t)k * D_DIM;
    float s = 0.f;
#pragma unroll
    for (int d = 0; d < D_DIM; ++d) s = fmaf(c[d], c[d], s);
    c2b[k] = s + SOFF;
}

// ---------------------------------------------------------------------------
// Split coords to f16 h/l AND pack into fragment order:
// dst = ((gt*4 + ds)*2 + n)*512 + lane*8 + j
//   cent = gt*32 + n*16 + l15, dim = ds*32 + quad*8 + j, lane = quad*16 + l15.
// A wave's (tile,step,n) fragment is then 1024 contiguous f16 = 64 lanes x 16B.
// ---------------------------------------------------------------------------
__global__ __launch_bounds__(256) void split_pack(const float* __restrict__ c,
                                                  f16* __restrict__ chp,
                                                  f16* __restrict__ clp) {
    int e = blockIdx.x * 256 + threadIdx.x;   // K*D source elements
    int cent = e >> 7, dim = e & 127;
    float x = c[e];
    f16 h = (f16)x;
    f16 l = (f16)(x - (float)h);
    int gt = cent >> 5, n = (cent >> 4) & 1, l15 = cent & 15;
    int ds = dim >> 5, quad = (dim >> 3) & 3, j = dim & 7;
    int lane = quad * 16 + l15;
    int dst = ((gt * 4 + ds) * 2 + n) * 512 + lane * 8 + j;
    chp[dst] = h;
    clp[dst] = l;
}

// ---------------------------------------------------------------------------
// Stage 1. Block = 4 waves x 64 points; latent (-2x) split h/l in XOR-swizzled
// LDS. Wave w scans cents [w*1024,(w+1)*1024) in 32-wide k-tiles (2 n-groups).
// Ping-pong invariant at tile top: Ba = (kt, ds0), offB -> (kt, ds1).
// key = (bits(score)&~63)|kn, kn = kt*2+n (6b); cent = (wave*64+kn)*16 + l15.
// ---------------------------------------------------------------------------
__global__ __launch_bounds__(256, 2) void argmin_mfma(
        const float* __restrict__ latent,
        const f16*   __restrict__ chp,    // packed B hi
        const f16*   __restrict__ clp,    // packed B lo
        const float* __restrict__ c2b,
        int* __restrict__ top1,
        int* __restrict__ top2) {
    __shared__ f16 latH[MB * 128];
    __shared__ f16 latL[MB * 128];
    __shared__ unsigned r1K[4][MB]; __shared__ int r1I[4][MB];
    __shared__ unsigned r2K[4][MB]; __shared__ int r2I[4][MB];

    const int t    = threadIdx.x;
    const int wave = t >> 6;
    const int lane = t & 63;
    const int quad = lane >> 4;
    const int l15  = lane & 15;
    const int row0 = blockIdx.x * MB;

    {   // Stage latent: scale -2, split h/l, XOR-swizzle 16-B units.
        const float4* src = (const float4*)(latent + (size_t)row0 * D_DIM);
#pragma unroll
        for (int i = 0; i < 4; ++i) {
            int g  = i * 256 + t;          // float8 index in [0,1024)
            int r  = g >> 4;               // row (16 float8 per row)
            int c8 = g & 15;               // logical 16-B column
            float4 v0 = src[2 * g];
            float4 v1 = src[2 * g + 1];
            float xs[8] = {v0.x, v0.y, v0.z, v0.w, v1.x, v1.y, v1.z, v1.w};
            f16x8 hv, lv;
#pragma unroll
            for (int c = 0; c < 8; ++c) {
                float x = -2.0f * xs[c];
                f16 h = (f16)x;
                hv[c] = h;
                lv[c] = (f16)(x - (float)h);
            }
            int pc = ((c8 ^ (r & 15)) << 3);
            *(f16x8*)&latH[r * 128 + pc] = hv;
            *(f16x8*)&latL[r * 128 + pc] = lv;
        }
    }
    __syncthreads();

    unsigned b1[16], b2[16];
#pragma unroll
    for (int i = 0; i < 16; ++i) { b1[i] = 0xFFFFFFFFu; b2[i] = 0xFFFFFFFFu; }

    const int wbase = wave * KW;
    // Packed-B element offset of the next step's load: uniform +1024/step.
    unsigned offB = (unsigned)(wave * 32 * 4) * 1024u + (unsigned)(lane * 8);

    // Named ping-pong regs — never address-taken.
    f16x8 Ba0, Ba1, Ba2, Ba3, Bb0, Bb1, Bb2, Bb3;
    f32x4 a00, a01, a10, a11, a20, a21, a30, a31;

#define PFB(P) \
    P##0 = *(const f16x8*)(chp + offB); \
    P##1 = *(const f16x8*)(clp + offB); \
    P##2 = *(const f16x8*)(chp + offB + 512); \
    P##3 = *(const f16x8*)(clp + offB + 512);

#define MF(d, a, b) d = __builtin_amdgcn_mfma_f32_16x16x32_f16(a, b, d, 0, 0, 0);

#define STEP(P, ds) { \
    const int pc_ = ((((ds) << 2) + quad) ^ l15) << 3; \
    f16x8 ah_, al_; \
    ah_ = *(const f16x8*)&latH[(     l15) * 128 + pc_]; \
    al_ = *(const f16x8*)&latL[(     l15) * 128 + pc_]; \
    MF(a00, ah_, P##0) MF(a00, ah_, P##1) MF(a00, al_, P##0) \
    MF(a01, ah_, P##2) MF(a01, ah_, P##3) MF(a01, al_, P##2) \
    ah_ = *(const f16x8*)&latH[(16 + l15) * 128 + pc_]; \
    al_ = *(const f16x8*)&latL[(16 + l15) * 128 + pc_]; \
    MF(a10, ah_, P##0) MF(a10, ah_, P##1) MF(a10, al_, P##0) \
    MF(a11, ah_, P##2) MF(a11, ah_, P##3) MF(a11, al_, P##2) \
    ah_ = *(const f16x8*)&latH[(32 + l15) * 128 + pc_]; \
    al_ = *(const f16x8*)&latL[(32 + l15) * 128 + pc_]; \
    MF(a20, ah_, P##0) MF(a20, ah_, P##1) MF(a20, al_, P##0) \
    MF(a21, ah_, P##2) MF(a21, ah_, P##3) MF(a21, al_, P##2) \
    ah_ = *(const f16x8*)&latH[(48 + l15) * 128 + pc_]; \
    al_ = *(const f16x8*)&latL[(48 + l15) * 128 + pc_]; \
    MF(a30, ah_, P##0) MF(a30, ah_, P##1) MF(a30, al_, P##0) \
    MF(a31, ah_, P##2) MF(a31, ah_, P##3) MF(a31, al_, P##2) }

#define INS1(s, kn, slot) { \
    unsigned key_ = (__float_as_uint(s) & 0xFFFFFFC0u) | (kn); \
    unsigned hi_ = key_ > b1[slot] ? key_ : b1[slot]; \
    b1[slot] = key_ < b1[slot] ? key_ : b1[slot]; \
    b2[slot] = hi_  < b2[slot] ? hi_  : b2[slot]; }

#define INS4(av, kn, m) \
    INS1(av[0], kn, (m) * 4 + 0) INS1(av[1], kn, (m) * 4 + 1) \
    INS1(av[2], kn, (m) * 4 + 2) INS1(av[3], kn, (m) * 4 + 3)

    // Prime: load (kt=0, ds=0) into Ba; offB -> (0, ds1).
    PFB(Ba)
    offB += 1024;
    float cv0 = c2b[wbase + l15];
    float cv1 = c2b[wbase + 16 + l15];

#pragma unroll 1
    for (int kt = 0; kt < KW / 32; ++kt) {
        a00 = (f32x4){cv0, cv0, cv0, cv0}; a01 = (f32x4){cv1, cv1, cv1, cv1};
        a10 = a00; a11 = a01; a20 = a00; a21 = a01; a30 = a00; a31 = a01;

        int ktn = (kt + 1) & 31;    // wraps at end; value then unused
        float cvn0 = c2b[wbase + ktn * 32 + l15];
        float cvn1 = c2b[wbase + ktn * 32 + 16 + l15];

        PFB(Bb) offB += 1024; STEP(Ba, 0)   // loads (kt,ds1)
        PFB(Ba) offB += 1024; STEP(Bb, 1)   // loads (kt,ds2)
        PFB(Bb) offB += 1024; STEP(Ba, 2)   // loads (kt,ds3); offB -> (kt+1,ds0)
        if (kt != KW / 32 - 1) { PFB(Ba) }  // loads (kt+1,ds0)
        offB += 1024;                       // -> (kt+1,ds1)
        STEP(Bb, 3)

        const unsigned kn0 = (unsigned)(kt * 2);
        const unsigned kn1 = kn0 + 1u;
        INS4(a00, kn0, 0) INS4(a10, kn0, 1) INS4(a20, kn0, 2) INS4(a30, kn0, 3)
        INS4(a01, kn1, 0) INS4(a11, kn1, 1) INS4(a21, kn1, 2) INS4(a31, kn1, 3)

        cv0 = cvn0; cv1 = cvn1;
    }

    // Quad butterfly: merge two sorted-2 (key,idx) lists per step.
#pragma unroll
    for (int m = 0; m < 4; ++m)
#pragma unroll
        for (int r = 0; r < 4; ++r) {
            unsigned k1 = b1[m * 4 + r], k2 = b2[m * 4 + r];
            int i1 = ((wave * 64 + (int)(k1 & 63u)) << 4) | l15;
            int i2 = ((wave * 64 + (int)(k2 & 63u)) << 4) | l15;
#pragma unroll
            for (int msk = 1; msk < 16; msk <<= 1) {
                unsigned ok1 = (unsigned)__shfl_xor((int)k1, msk, 64);
                int      oi1 = __shfl_xor(i1, msk, 64);
                unsigned ok2 = (unsigned)__shfl_xor((int)k2, msk, 64);
                int      oi2 = __shfl_xor(i2, msk, 64);
                bool ow = ok1 < k1;
                unsigned w1k = ow ? ok1 : k1; int w1i = ow ? oi1 : i1;
                unsigned lsk = ow ? k1 : ok1; int lsi = ow ? i1 : oi1;
                unsigned wsk = ow ? ok2 : k2; int wsi = ow ? oi2 : i2;
                bool sw = lsk < wsk;
                k1 = w1k; i1 = w1i;
                k2 = sw ? lsk : wsk; i2 = sw ? lsi : wsi;
            }
            if (l15 == 0) {
                int p = m * 16 + quad * 4 + r;
                r1K[wave][p] = k1; r1I[wave][p] = i1;
                r2K[wave][p] = k2; r2I[wave][p] = i2;
            }
        }
    __syncthreads();

    if (t < MB) {
        unsigned k1 = r1K[0][t], k2 = r2K[0][t];
        int      i1 = r1I[0][t], i2 = r2I[0][t];
#pragma unroll
        for (int w = 1; w < 4; ++w) {
            unsigned ok1 = r1K[w][t], ok2 = r2K[w][t];
            int      oi1 = r1I[w][t], oi2 = r2I[w][t];
            bool ow = ok1 < k1;
            unsigned w1k = ow ? ok1 : k1; int w1i = ow ? oi1 : i1;
            unsigned lsk = ow ? k1 : ok1; int lsi = ow ? i1 : oi1;
            unsigned wsk = ow ? ok2 : k2; int wsi = ow ? oi2 : i2;
            bool sw = lsk < wsk;
            k1 = w1k; i1 = w1i;
            k2 = sw ? lsk : wsk; i2 = sw ? lsi : wsi;
        }
        top1[row0 + t] = i1;
        top2[row0 + t] = i2;
    }
}

// ---------------------------------------------------------------------------
// Stage 2: exact fp64 rescore of the two candidates; true winner wins
// (idx tie -> smaller index).
// ---------------------------------------------------------------------------
__global__ __launch_bounds__(256) void rescore(const float* __restrict__ latent,
                                               const float* __restrict__ coords,
                                               const int* __restrict__ top1,
                                               const int* __restrict__ top2,
                                               int* __restrict__ out) {
    int n = blockIdx.x * 256 + threadIdx.x;
    int i1 = top1[n], i2 = top2[n];
    const float* x  = latent + (size_t)n * D_DIM;
    const float* ca = coords + (size_t)i1 * D_DIM;
    const float* cb = coords + (size_t)i2 * D_DIM;
    double d1 = 0.0, d2 = 0.0;
#pragma unroll
    for (int d = 0; d < D_DIM; d += 4) {
        float4 xv = *(const float4*)(x + d);
        float4 av = *(const float4*)(ca + d);
        float4 bv = *(const float4*)(cb + d);
        double e;
        e = (double)xv.x - (double)av.x; d1 += e * e;
        e = (double)xv.y - (double)av.y; d1 += e * e;
        e = (double)xv.z - (double)av.z; d1 += e * e;
        e = (double)xv.w - (double)av.w; d1 += e * e;
        e = (double)xv.x - (double)bv.x; d2 += e * e;
        e = (double)xv.y - (double)bv.y; d2 += e * e;
        e = (double)xv.z - (double)bv.z; d2 += e * e;
        e = (double)xv.w - (double)bv.w; d2 += e * e;
    }
    bool second = (d2 < d1) || (d2 == d1 && i2 < i1);
    out[n] = second ? i2 : i1;
}

// ---------------------------------------------------------------------------
extern "C" void kernel_launch(void* const* d_in, const int* in_sizes, int n_in,
                              void* d_out, int out_size, void* d_ws, size_t ws_size,
                              hipStream_t stream) {
    const float* latent = (const float*)d_in[0];
    const float* coords = (const float*)d_in[1];
    int* out = (int*)d_out;

    // ws: chp [K*D] f16 | clp [K*D] f16 | c2b [K] f32 | top1 [N] | top2 [N]
    f16*   chp = (f16*)d_ws;
    f16*   clp = chp + (size_t)K_CENT * D_DIM;
    float* c2b = (float*)(clp + (size_t)K_CENT * D_DIM);
    int*   t1  = (int*)(c2b + K_CENT);
    int*   t2  = t1 + N_PTS;

    c2_kernel<<<dim3(K_CENT / 256), dim3(256), 0, stream>>>(coords, c2b);
    split_pack<<<dim3(K_CENT * D_DIM / 256), dim3(256), 0, stream>>>(coords, chp, clp);
    argmin_mfma<<<dim3(N_PTS / MB), dim3(256), 0, stream>>>(latent, chp, clp, c2b, t1, t2);
    rescore<<<dim3(N_PTS / 256), dim3(256), 0, stream>>>(latent, coords, t1, t2, out);
}